// Round 12
// baseline (259.571 us; speedup 1.0000x reference)
//
#include <hip/hip_runtime.h>

#define IN_NODE 128
#define OUT_NODE 64
#define NHEAD 4
#define HN 256                 // NHEAD * OUT_NODE
#define HE 64                  // NHEAD * OUT_EDGE
#define LEAKY 0.01f

typedef __attribute__((ext_vector_type(8))) short bf16x8;
typedef __attribute__((ext_vector_type(4))) float f32x4;
typedef __attribute__((ext_vector_type(2))) float f32x2;

__device__ __forceinline__ float bf2f(unsigned short u) {
    union { unsigned u; float f; } v; v.u = ((unsigned)u) << 16; return v.f;
}
__device__ __forceinline__ unsigned short f2bf(float x) {
    union { float f; unsigned u; } v; v.f = x;
    unsigned r = v.u + 0x7FFF + ((v.u >> 16) & 1);   // RNE
    return (unsigned short)(r >> 16);
}
__device__ __forceinline__ bf16x8 cvt8(float4 a, float4 b) {
    bf16x8 r;
    r[0] = (short)f2bf(a.x); r[1] = (short)f2bf(a.y);
    r[2] = (short)f2bf(a.z); r[3] = (short)f2bf(a.w);
    r[4] = (short)f2bf(b.x); r[5] = (short)f2bf(b.y);
    r[6] = (short)f2bf(b.z); r[7] = (short)f2bf(b.w);
    return r;
}
// one dword holding 2 bf16 -> 2 f32 (lo = element 2k, hi = element 2k+1)
__device__ __forceinline__ f32x2 bfcvt2(unsigned d) {
    union { unsigned u; float f; } lo, hi;
    lo.u = d << 16; hi.u = d & 0xFFFF0000u;
    f32x2 r; r.x = lo.f; r.y = hi.f; return r;
}

// ------ prep_w: wsum (block 0) + W -> fragment-contiguous bf16 WB (1..12) ---
__global__ void prep_w(const float* __restrict__ W_fij,
                       const float* __restrict__ W_ni,
                       const float* __restrict__ W_ns,
                       const float* __restrict__ W_nj,
                       float* __restrict__ wsum, unsigned short* __restrict__ WT) {
    int b = blockIdx.x;
    if (b == 0) {
        int k = threadIdx.x;
        if (k < 64) {
            float s = 0.f;
#pragma unroll
            for (int c = 0; c < 16; ++c) s += W_fij[c * 64 + k];
            wsum[k] = s;
        }
        return;
    }
    int base = (b - 1) * 4096 + threadIdx.x;
#pragma unroll
    for (int i = 0; i < 16; ++i) {
        int idx = base + i * 256;
        int g   = idx >> 11;          // group (24)
        int rem = idx & 2047;
        int c   = rem >> 9;           // K-chunk (4)
        int l   = (rem >> 3) & 63;    // lane
        int j   = rem & 7;            // element within fragment
        int nl  = l & 15;
        int k   = c * 32 + (l >> 4) * 8 + j;
        unsigned short v;
        if (g < 4)       v = f2bf(W_ni[k * 64  + g * 16 + nl]);
        else if (g < 20) v = f2bf(W_ns[k * 256 + (g - 4) * 16 + nl]);
        else             v = f2bf(W_nj[k * 64  + (g - 20) * 16 + nl]);
        WT[idx] = v;
    }
}

// ------- scan_all: full exclusive scan of cnt -> row_ptr, one dispatch ------
__global__ __launch_bounds__(256) void scan_all(const int* __restrict__ cnt,
                                                int* __restrict__ row_ptr,
                                                int* __restrict__ partials,
                                                int* __restrict__ flags,
                                                int n, int E, int nb) {
    __shared__ int sums[256];
    __shared__ int s_base;
    int tid = threadIdx.x, b = blockIdx.x;
    int base = b * 1024;
    int v[4]; int tsum = 0;
#pragma unroll
    for (int j = 0; j < 4; ++j) {
        int idx = base + tid * 4 + j;
        v[j] = (idx < n) ? cnt[idx] : 0;
        tsum += v[j];
    }
    sums[tid] = tsum;
    __syncthreads();
    for (int off = 1; off < 256; off <<= 1) {
        int x = (tid >= off) ? sums[tid - off] : 0;
        __syncthreads();
        sums[tid] += x;
        __syncthreads();
    }
    if (tid == 255) {
        __hip_atomic_store(&partials[b], sums[255], __ATOMIC_RELAXED, __HIP_MEMORY_SCOPE_AGENT);
        __hip_atomic_store(&flags[b], 1, __ATOMIC_RELEASE, __HIP_MEMORY_SCOPE_AGENT);
    }
    if (tid < 64) {
        int val = 0;
        if (tid < nb) {
            while (__hip_atomic_load(&flags[tid], __ATOMIC_ACQUIRE, __HIP_MEMORY_SCOPE_AGENT) == 0) {
                __builtin_amdgcn_s_sleep(1);
            }
            val = __hip_atomic_load(&partials[tid], __ATOMIC_RELAXED, __HIP_MEMORY_SCOPE_AGENT);
        }
#pragma unroll
        for (int o = 1; o < 64; o <<= 1) {
            int x = __shfl_up(val, o);
            if (tid >= o) val += x;
        }
        int off = (b > 0) ? __shfl(val, b - 1) : 0;
        if (tid == 0) s_base = off;
    }
    __syncthreads();
    int run = s_base + sums[tid] - tsum;   // global exclusive prefix
#pragma unroll
    for (int j = 0; j < 4; ++j) {
        int idx = base + tid * 4 + j;
        if (idx < n) row_ptr[idx] = run;
        run += v[j];
    }
    if (b == nb - 1 && tid == 0) row_ptr[n] = E;
}

// ---- GEMM tile: 64 rows of A x (NG*16) output cols, A staged in LDS once ---
template<int NG, int G0>
__device__ __forceinline__ void gemm_tile(
    const float* __restrict__ A, int rowBase, int M,
    const unsigned short* __restrict__ WB, const float* __restrict__ b_ns,
    unsigned short* __restrict__ f_ni, unsigned short* __restrict__ h_src,
    unsigned short* __restrict__ f_nj, unsigned short* As)
{
    const int t = threadIdx.x;
    const float4* A4 = reinterpret_cast<const float4*>(A);
#pragma unroll
    for (int j = 0; j < 4; ++j) {
        int gi = j * 256 + t;            // granule index (8 floats)
        int r  = gi >> 4;                // tile row (0..63)
        int gr = rowBase + r; if (gr >= M) gr = M - 1;   // clamp, stores guarded
        int fi = (gi & 15) * 2;          // float4 index within row
        float4 a0 = A4[(size_t)gr * 32 + fi];
        float4 a1 = A4[(size_t)gr * 32 + fi + 1];
        int byteoff = (gi * 16) ^ ((r & 7) << 4);
        *reinterpret_cast<bf16x8*>(reinterpret_cast<char*>(As) + byteoff) = cvt8(a0, a1);
    }
    __syncthreads();

    const int lane = t & 63, w = t >> 6;
    const int rw = rowBase + w * 16;
    if (rw >= M) return;                 // tail wave, nothing to compute
    const int m = lane & 15, q = lane >> 4;
    const int tr = w * 16 + m;

    f32x4 acc[NG] = {};
    const char* Asb = reinterpret_cast<const char*>(As);
#pragma unroll
    for (int c = 0; c < 4; ++c) {
        int gi  = tr * 16 + c * 4 + q;
        int off = (gi * 16) ^ ((tr & 7) << 4);
        bf16x8 af = *reinterpret_cast<const bf16x8*>(Asb + off);
#pragma unroll
        for (int g = 0; g < NG; ++g) {
            bf16x8 bf = *reinterpret_cast<const bf16x8*>(
                WB + (size_t)(((G0 + g) * 4 + c) * 64 + lane) * 8);
            acc[g] = __builtin_amdgcn_mfma_f32_16x16x32_bf16(af, bf, acc[g], 0, 0, 0);
        }
    }

#pragma unroll
    for (int g = 0; g < NG; ++g) {
        const int ga = G0 + g;
        unsigned short* C; int N, colBase; const float* bias = nullptr;
        if (ga < 4)       { C = f_ni;  N = 64;  colBase = ga * 16; }
        else if (ga < 20) { C = h_src; N = 256; colBase = (ga - 4) * 16; bias = b_ns; }
        else              { C = f_nj;  N = 64;  colBase = (ga - 20) * 16; }
        int col = colBase + m;
        float bv = bias ? bias[col] : 0.f;
#pragma unroll
        for (int rr = 0; rr < 4; ++rr) {
            int orow = rw + q * 4 + rr;
            if (orow < M) C[(size_t)orow * N + col] = f2bf(acc[g][rr] + bv);
        }
    }
}

// -------- hist_gemm: degree histogram (rank capture)  ||  ALL GEMM tiles ----
// Histogram (L2-atomic path) and GEMM (MFMA/LDS path) use complementary
// resources; striping them 1:1 hides the ~40us histogram behind the GEMM
// instead of serializing it before everything. Role bodies verbatim from the
// proven round-7 prep_hist / mega kernels.
__global__ __launch_bounds__(256) void hist_gemm(
    const float* __restrict__ nfeats, const float* __restrict__ dst_feats,
    const unsigned short* __restrict__ WT, const float* __restrict__ b_ns,
    const int* __restrict__ dst,
    int* __restrict__ cnt, int* __restrict__ rank,
    unsigned short* __restrict__ f_ni, unsigned short* __restrict__ h_src,
    unsigned short* __restrict__ f_nj,
    int Ns, int Nd, int E, int nBlkNf, int nBlkDj)
{
    __shared__ __align__(16) unsigned short As[64 * 128];
    const int g = blockIdx.x >> 1, r = blockIdx.x & 1;
    if (r == 1) {                               // ---- GEMM role ----
        if (g < 2 * nBlkNf) {
            int tile = g >> 1;
            if ((g & 1) == 0)
                gemm_tile<10, 0>(nfeats, tile * 64, Ns, WT, b_ns, f_ni, h_src, f_nj, As);
            else
                gemm_tile<10, 10>(nfeats, tile * 64, Ns, WT, b_ns, f_ni, h_src, f_nj, As);
        } else if (g < 2 * nBlkNf + nBlkDj) {
            gemm_tile<4, 20>(dst_feats, (g - 2 * nBlkNf) * 64, Nd, WT, b_ns, f_ni, h_src, f_nj, As);
        }
        return;
    }
    // ---- histogram role ----
    int i = g * 256 + threadIdx.x;
    if (i < E) rank[i] = atomicAdd(&cnt[dst[i]], 1);   // rank = old count
}

// -------- scatter_k: atomic-free CSR scatter (rank precomputed) -------------
__global__ __launch_bounds__(256) void scatter_k(
    const int* __restrict__ src, const int* __restrict__ dst,
    const float* __restrict__ reward, const int* __restrict__ row_ptr,
    const int* __restrict__ rank, int2* __restrict__ sr_s, int E)
{
    int i = blockIdx.x * 256 + threadIdx.x;
    if (i >= E) return;
    int d = dst[i];
    sr_s[row_ptr[d] + rank[i]] = make_int2(src[i], __float_as_int(reward[i]));
}

// ------- fused logits + softmax + aggregation: head-aligned gather ----------
// (byte-identical to the proven round-7/10 version: ~69us, VGPR 36, occ ~60%,
// 0 bank conflicts). One dst per wave. Subgroup (16 lanes) owns one edge per
// quad; lane gathers its OWN head's 32 B of h_src -> zero broadcast shuffles.
// Depth-1 pipeline (avg degree 16 -> nq~4; deeper = prologue/drain + VGPR).
struct G { uint2 ui; uint4 h0; uint4 h1; };
__device__ __forceinline__ G gatherE(const unsigned short* __restrict__ f_ni,
                                     const unsigned short* __restrict__ h_src,
                                     int sn, int ll, int hq) {
    G g;
    g.ui = *reinterpret_cast<const uint2*>(f_ni + (size_t)sn * HE + 4 * ll);
    const unsigned short* hp = h_src + (size_t)sn * HN + hq;
    g.h0 = *reinterpret_cast<const uint4*>(hp);
    g.h1 = *reinterpret_cast<const uint4*>(hp + 8);
    return g;
}

__global__ __launch_bounds__(256) void fused_agg(
    const unsigned short* __restrict__ f_ni, const unsigned short* __restrict__ f_nj,
    const unsigned short* __restrict__ h_src, const int2* __restrict__ sr_s,
    const int* __restrict__ row_ptr,
    const float* __restrict__ wsum, const float* __restrict__ b_e,
    const float* __restrict__ attn, float* __restrict__ out, int Nd)
{
    __shared__ float red[4][1024];
    const int wv = threadIdx.x >> 6, lane = threadIdx.x & 63;
    const int d = blockIdx.x * 4 + wv;
    if (d >= Nd) return;
    const int ll = lane & 15, sub = lane >> 4;
    const int hq = ((lane >> 2) & 3) * 64 + (lane & 3) * 16;  // head*64 + chunk*16
    const int mql = (lane >> 1) & 3;                          // write swizzle

    // wave-invariant per-lane constants
    float4 wsv = *reinterpret_cast<const float4*>(wsum + 4 * ll);
    float4 bev = *reinterpret_cast<const float4*>(b_e + 4 * ll);
    float4 atv = *reinterpret_cast<const float4*>(attn + 4 * ll);
    f32x2 ws01 = {wsv.x, wsv.y}, ws23 = {wsv.z, wsv.w};
    f32x2 at01 = {atv.x, atv.y}, at23 = {atv.z, atv.w};
    const f32x2 lk2 = {LEAKY, LEAKY};

    const int beg = row_ptr[d];
    const int end = row_ptr[d + 1];
    const int deg = end - beg;

    float den = 0.f;
    f32x2 a0 = {}, a1 = {}, a2 = {}, a3 = {}, a4 = {}, a5 = {}, a6 = {}, a7 = {};

    if (deg > 0) {
        uint2 uj = *reinterpret_cast<const uint2*>(f_nj + (size_t)d * HE + 4 * ll);
        f32x2 bb01 = bfcvt2(uj.x) + (f32x2){bev.x, bev.y};
        f32x2 bb23 = bfcvt2(uj.y) + (f32x2){bev.z, bev.w};
        const int nq = (deg + 3) >> 2;
        const int last = end - 1;

#define LDSR(q) ({ int qq_ = ((q) < nq) ? (q) : (nq - 1);                 \
                   int slot_ = beg + qq_ * 4 + sub;                       \
                   if (slot_ > last) slot_ = last;                        \
                   sr_s[slot_]; })

#define COMPUTE(sr, gg, kq) do {                                          \
    float r_ = __int_as_float((sr).y);                                    \
    f32x2 r2_ = {r_, r_};                                                 \
    f32x2 v01_ = bfcvt2((gg).ui.x) + r2_ * ws01 + bb01;                   \
    f32x2 v23_ = bfcvt2((gg).ui.y) + r2_ * ws23 + bb23;                   \
    v01_ = __builtin_elementwise_max(v01_, v01_ * lk2);                   \
    v23_ = __builtin_elementwise_max(v23_, v23_ * lk2);                   \
    f32x2 t2_ = v01_ * at01 + v23_ * at23;                                \
    float t_ = t2_.x + t2_.y;                                             \
    t_ += __shfl_xor(t_, 1);                                              \
    t_ += __shfl_xor(t_, 2);                                              \
    float ev_ = ((beg + (kq) * 4 + sub) < end) ? __expf(t_) : 0.f;        \
    den += ev_;                                                           \
    f32x2 ev2_ = {ev_, ev_};                                              \
    a0 += bfcvt2((gg).h0.x) * ev2_;                                       \
    a1 += bfcvt2((gg).h0.y) * ev2_;                                       \
    a2 += bfcvt2((gg).h0.z) * ev2_;                                       \
    a3 += bfcvt2((gg).h0.w) * ev2_;                                       \
    a4 += bfcvt2((gg).h1.x) * ev2_;                                       \
    a5 += bfcvt2((gg).h1.y) * ev2_;                                       \
    a6 += bfcvt2((gg).h1.z) * ev2_;                                       \
    a7 += bfcvt2((gg).h1.w) * ev2_;                                       \
} while (0)

        int2 sr0 = LDSR(0), sr1 = LDSR(1);
        G gA = gatherE(f_ni, h_src, sr0.x, ll, hq);
        for (int k = 0; k < nq; ++k) {
            int2 sr2 = LDSR(k + 2);
            G gB = gatherE(f_ni, h_src, sr1.x, ll, hq);
            COMPUTE(sr0, gA, k);
            sr0 = sr1; sr1 = sr2; gA = gB;
        }
#undef COMPUTE
#undef LDSR
    }

    // ---- epilogue: per-head den (lane's own head), swizzled LDS reduce ----
    den += __shfl_xor(den, 16);
    den += __shfl_xor(den, 32);           // lane now has ITS head's total
    float sc = (den > 0.f) ? 0.25f / den : 0.f;
    float* wr = &red[wv][lane * 16];
    float4 s0 = {a0.x * sc, a0.y * sc, a1.x * sc, a1.y * sc};
    float4 s1 = {a2.x * sc, a2.y * sc, a3.x * sc, a3.y * sc};
    float4 s2 = {a4.x * sc, a4.y * sc, a5.x * sc, a5.y * sc};
    float4 s3 = {a6.x * sc, a6.y * sc, a7.x * sc, a7.y * sc};
    *reinterpret_cast<float4*>(wr + ((0 ^ mql) << 2)) = s0;
    *reinterpret_cast<float4*>(wr + ((1 ^ mql) << 2)) = s1;
    *reinterpret_cast<float4*>(wr + ((2 ^ mql) << 2)) = s2;
    *reinterpret_cast<float4*>(wr + ((3 ^ mql) << 2)) = s3;
    asm volatile("s_waitcnt lgkmcnt(0)" ::: "memory");
    float ssum = 0.f;
    const int e = lane & 15, c45 = lane >> 4;
#pragma unroll
    for (int s = 0; s < 4; ++s)
#pragma unroll
        for (int h = 0; h < 4; ++h) {
            int L = s * 16 + h * 4 + c45;          // writer lane
            int m2 = (L >> 1) & 3;                 // its swizzle
            int fi = L * 16 + (((e >> 2) ^ m2) << 2) + (e & 3);
            ssum += red[wv][fi];
        }
    out[(size_t)d * OUT_NODE + lane] = fmaxf(ssum, 0.f);
}

static inline char* align256(char* p) {
    return (char*)(((uintptr_t)p + 255) & ~(uintptr_t)255);
}

extern "C" void kernel_launch(void* const* d_in, const int* in_sizes, int n_in,
                              void* d_out, int out_size, void* d_ws, size_t ws_size,
                              hipStream_t stream) {
    const float* nfeats    = (const float*)d_in[0];
    const float* dst_feats = (const float*)d_in[1];
    const float* reward    = (const float*)d_in[2];
    const int*   src       = (const int*)d_in[3];
    const int*   dst       = (const int*)d_in[4];
    const float* W_ns      = (const float*)d_in[5];
    const float* b_ns      = (const float*)d_in[6];
    const float* W_ni      = (const float*)d_in[7];
    const float* W_nj      = (const float*)d_in[8];
    const float* W_fij     = (const float*)d_in[9];
    const float* attn      = (const float*)d_in[10];
    const float* b_e       = (const float*)d_in[11];
    float* out = (float*)d_out;

    const int Ns = in_sizes[0] / IN_NODE;
    const int Nd = in_sizes[1] / IN_NODE;
    const int E  = in_sizes[2];

    char* ws = (char*)d_ws;
    unsigned short* f_ni  = (unsigned short*)ws; ws = align256(ws + (size_t)Ns * HE * 2);
    unsigned short* f_nj  = (unsigned short*)ws; ws = align256(ws + (size_t)Nd * HE * 2);
    unsigned short* h_src = (unsigned short*)ws; ws = align256(ws + (size_t)Ns * HN * 2);
    unsigned short* WT    = (unsigned short*)ws; ws = align256(ws + 49152 * 2);
    float* wsum    = (float*)ws; ws = align256(ws + HE * 4);
    int*   cnt     = (int*)ws;   // cnt + flags zeroed by one memset
    int*   flags   = cnt + Nd;   ws = align256(ws + (size_t)(Nd + 64) * 4);
    int*   row_ptr = (int*)ws;   ws = align256(ws + (size_t)(Nd + 1) * 4);
    int*   partials= (int*)ws;   ws = align256(ws + 256 * 4);
    int2*  sr_s    = (int2*)ws;  ws = align256(ws + (size_t)E * 8);
    int*   rank    = (int*)ws;   ws = align256(ws + (size_t)E * 4);

    hipMemsetAsync(cnt, 0, (size_t)(Nd + 64) * 4, stream);

    prep_w<<<13, 256, 0, stream>>>(W_fij, W_ni, W_ns, W_nj, wsum, WT);

    int nBlkNf = (Ns + 63) / 64;
    int nBlkDj = (Nd + 63) / 64;
    int nU = 2 * nBlkNf + nBlkDj;          // gemm units
    int nHist = (E + 255) / 256;           // histogram blocks
    int nGroups = (nHist > nU) ? nHist : nU;
    hist_gemm<<<nGroups * 2, 256, 0, stream>>>(
        nfeats, dst_feats, WT, b_ns, dst, cnt, rank,
        f_ni, h_src, f_nj, Ns, Nd, E, nBlkNf, nBlkDj);

    int nb = (Nd + 1023) / 1024;
    scan_all<<<nb, 256, 0, stream>>>(cnt, row_ptr, partials, flags, Nd, E, nb);

    scatter_k<<<(E + 255) / 256, 256, 0, stream>>>(
        src, dst, reward, row_ptr, rank, sr_s, E);

    fused_agg<<<(Nd + 3) / 4, 256, 0, stream>>>(
        f_ni, f_nj, h_src, sr_s, row_ptr, wsum, b_e, attn, out, Nd);
}

// Round 13
// 253.087 us; speedup vs baseline: 1.0256x; 1.0256x over previous
//
#include <hip/hip_runtime.h>

#define IN_NODE 128
#define OUT_NODE 64
#define NHEAD 4
#define HN 256                 // NHEAD * OUT_NODE
#define HE 64                  // NHEAD * OUT_EDGE
#define LEAKY 0.01f

typedef __attribute__((ext_vector_type(8))) short bf16x8;
typedef __attribute__((ext_vector_type(4))) float f32x4;
typedef __attribute__((ext_vector_type(2))) float f32x2;

__device__ __forceinline__ float bf2f(unsigned short u) {
    union { unsigned u; float f; } v; v.u = ((unsigned)u) << 16; return v.f;
}
__device__ __forceinline__ unsigned short f2bf(float x) {
    union { float f; unsigned u; } v; v.f = x;
    unsigned r = v.u + 0x7FFF + ((v.u >> 16) & 1);   // RNE
    return (unsigned short)(r >> 16);
}
__device__ __forceinline__ bf16x8 cvt8(float4 a, float4 b) {
    bf16x8 r;
    r[0] = (short)f2bf(a.x); r[1] = (short)f2bf(a.y);
    r[2] = (short)f2bf(a.z); r[3] = (short)f2bf(a.w);
    r[4] = (short)f2bf(b.x); r[5] = (short)f2bf(b.y);
    r[6] = (short)f2bf(b.z); r[7] = (short)f2bf(b.w);
    return r;
}
// one dword holding 2 bf16 -> 2 f32 (lo = element 2k, hi = element 2k+1)
__device__ __forceinline__ f32x2 bfcvt2(unsigned d) {
    union { unsigned u; float f; } lo, hi;
    lo.u = d << 16; hi.u = d & 0xFFFF0000u;
    f32x2 r; r.x = lo.f; r.y = hi.f; return r;
}

// ------ prep_w: wsum (block 0) + W -> fragment-contiguous bf16 WB (1..12) ---
__global__ void prep_w(const float* __restrict__ W_fij,
                       const float* __restrict__ W_ni,
                       const float* __restrict__ W_ns,
                       const float* __restrict__ W_nj,
                       float* __restrict__ wsum, unsigned short* __restrict__ WT) {
    int b = blockIdx.x;
    if (b == 0) {
        int k = threadIdx.x;
        if (k < 64) {
            float s = 0.f;
#pragma unroll
            for (int c = 0; c < 16; ++c) s += W_fij[c * 64 + k];
            wsum[k] = s;
        }
        return;
    }
    int base = (b - 1) * 4096 + threadIdx.x;
#pragma unroll
    for (int i = 0; i < 16; ++i) {
        int idx = base + i * 256;
        int g   = idx >> 11;          // group (24)
        int rem = idx & 2047;
        int c   = rem >> 9;           // K-chunk (4)
        int l   = (rem >> 3) & 63;    // lane
        int j   = rem & 7;            // element within fragment
        int nl  = l & 15;
        int k   = c * 32 + (l >> 4) * 8 + j;
        unsigned short v;
        if (g < 4)       v = f2bf(W_ni[k * 64  + g * 16 + nl]);
        else if (g < 20) v = f2bf(W_ns[k * 256 + (g - 4) * 16 + nl]);
        else             v = f2bf(W_nj[k * 64  + (g - 20) * 16 + nl]);
        WT[idx] = v;
    }
}

// ------- scan_all: full exclusive scan of cnt -> row_ptr, one dispatch ------
__global__ __launch_bounds__(256) void scan_all(const int* __restrict__ cnt,
                                                int* __restrict__ row_ptr,
                                                int* __restrict__ partials,
                                                int* __restrict__ flags,
                                                int n, int E, int nb) {
    __shared__ int sums[256];
    __shared__ int s_base;
    int tid = threadIdx.x, b = blockIdx.x;
    int base = b * 1024;
    int v[4]; int tsum = 0;
#pragma unroll
    for (int j = 0; j < 4; ++j) {
        int idx = base + tid * 4 + j;
        v[j] = (idx < n) ? cnt[idx] : 0;
        tsum += v[j];
    }
    sums[tid] = tsum;
    __syncthreads();
    for (int off = 1; off < 256; off <<= 1) {
        int x = (tid >= off) ? sums[tid - off] : 0;
        __syncthreads();
        sums[tid] += x;
        __syncthreads();
    }
    if (tid == 255) {
        __hip_atomic_store(&partials[b], sums[255], __ATOMIC_RELAXED, __HIP_MEMORY_SCOPE_AGENT);
        __hip_atomic_store(&flags[b], 1, __ATOMIC_RELEASE, __HIP_MEMORY_SCOPE_AGENT);
    }
    if (tid < 64) {
        int val = 0;
        if (tid < nb) {
            while (__hip_atomic_load(&flags[tid], __ATOMIC_ACQUIRE, __HIP_MEMORY_SCOPE_AGENT) == 0) {
                __builtin_amdgcn_s_sleep(1);
            }
            val = __hip_atomic_load(&partials[tid], __ATOMIC_RELAXED, __HIP_MEMORY_SCOPE_AGENT);
        }
#pragma unroll
        for (int o = 1; o < 64; o <<= 1) {
            int x = __shfl_up(val, o);
            if (tid >= o) val += x;
        }
        int off = (b > 0) ? __shfl(val, b - 1) : 0;
        if (tid == 0) s_base = off;
    }
    __syncthreads();
    int run = s_base + sums[tid] - tsum;   // global exclusive prefix
#pragma unroll
    for (int j = 0; j < 4; ++j) {
        int idx = base + tid * 4 + j;
        if (idx < n) row_ptr[idx] = run;
        run += v[j];
    }
    if (b == nb - 1 && tid == 0) row_ptr[n] = E;
}

// ---- GEMM tile: 64 rows of A x (NG*16) output cols, A staged in LDS once ---
template<int NG, int G0>
__device__ __forceinline__ void gemm_tile(
    const float* __restrict__ A, int rowBase, int M,
    const unsigned short* __restrict__ WB, const float* __restrict__ b_ns,
    unsigned short* __restrict__ f_ni, unsigned short* __restrict__ h_src,
    unsigned short* __restrict__ f_nj, unsigned short* As)
{
    const int t = threadIdx.x;
    const float4* A4 = reinterpret_cast<const float4*>(A);
#pragma unroll
    for (int j = 0; j < 4; ++j) {
        int gi = j * 256 + t;            // granule index (8 floats)
        int r  = gi >> 4;                // tile row (0..63)
        int gr = rowBase + r; if (gr >= M) gr = M - 1;   // clamp, stores guarded
        int fi = (gi & 15) * 2;          // float4 index within row
        float4 a0 = A4[(size_t)gr * 32 + fi];
        float4 a1 = A4[(size_t)gr * 32 + fi + 1];
        int byteoff = (gi * 16) ^ ((r & 7) << 4);
        *reinterpret_cast<bf16x8*>(reinterpret_cast<char*>(As) + byteoff) = cvt8(a0, a1);
    }
    __syncthreads();

    const int lane = t & 63, w = t >> 6;
    const int rw = rowBase + w * 16;
    if (rw >= M) return;                 // tail wave, nothing to compute
    const int m = lane & 15, q = lane >> 4;
    const int tr = w * 16 + m;

    f32x4 acc[NG] = {};
    const char* Asb = reinterpret_cast<const char*>(As);
#pragma unroll
    for (int c = 0; c < 4; ++c) {
        int gi  = tr * 16 + c * 4 + q;
        int off = (gi * 16) ^ ((tr & 7) << 4);
        bf16x8 af = *reinterpret_cast<const bf16x8*>(Asb + off);
#pragma unroll
        for (int g = 0; g < NG; ++g) {
            bf16x8 bf = *reinterpret_cast<const bf16x8*>(
                WB + (size_t)(((G0 + g) * 4 + c) * 64 + lane) * 8);
            acc[g] = __builtin_amdgcn_mfma_f32_16x16x32_bf16(af, bf, acc[g], 0, 0, 0);
        }
    }

#pragma unroll
    for (int g = 0; g < NG; ++g) {
        const int ga = G0 + g;
        unsigned short* C; int N, colBase; const float* bias = nullptr;
        if (ga < 4)       { C = f_ni;  N = 64;  colBase = ga * 16; }
        else if (ga < 20) { C = h_src; N = 256; colBase = (ga - 4) * 16; bias = b_ns; }
        else              { C = f_nj;  N = 64;  colBase = (ga - 20) * 16; }
        int col = colBase + m;
        float bv = bias ? bias[col] : 0.f;
#pragma unroll
        for (int rr = 0; rr < 4; ++rr) {
            int orow = rw + q * 4 + rr;
            if (orow < M) C[(size_t)orow * N + col] = f2bf(acc[g][rr] + bv);
        }
    }
}

// GEMM unit decode shared by both mixed kernels: unit u in [0, 2*nBlkNf+nBlkDj)
__device__ __forceinline__ void gemm_unit(
    int u, const float* __restrict__ nfeats, const float* __restrict__ dst_feats,
    const unsigned short* __restrict__ WT, const float* __restrict__ b_ns,
    unsigned short* __restrict__ f_ni, unsigned short* __restrict__ h_src,
    unsigned short* __restrict__ f_nj, unsigned short* As,
    int Ns, int Nd, int nBlkNf, int nBlkDj)
{
    if (u < 2 * nBlkNf) {
        int tile = u >> 1;
        if ((u & 1) == 0)
            gemm_tile<10, 0>(nfeats, tile * 64, Ns, WT, b_ns, f_ni, h_src, f_nj, As);
        else
            gemm_tile<10, 10>(nfeats, tile * 64, Ns, WT, b_ns, f_ni, h_src, f_nj, As);
    } else if (u < 2 * nBlkNf + nBlkDj) {
        gemm_tile<4, 20>(dst_feats, (u - 2 * nBlkNf) * 64, Nd, WT, b_ns, f_ni, h_src, f_nj, As);
    }
}

// -------- hist_gemm: degree histogram (rank capture) || GEMM units [u0,u1) --
// The ~800K random L2 RMWs (the phase floor, ~55-60us standalone) hide the
// GEMM half running on the MFMA/LDS path.
__global__ __launch_bounds__(256) void hist_gemm(
    const float* __restrict__ nfeats, const float* __restrict__ dst_feats,
    const unsigned short* __restrict__ WT, const float* __restrict__ b_ns,
    const int* __restrict__ dst,
    int* __restrict__ cnt, int* __restrict__ rank,
    unsigned short* __restrict__ f_ni, unsigned short* __restrict__ h_src,
    unsigned short* __restrict__ f_nj,
    int Ns, int Nd, int E, int nBlkNf, int nBlkDj, int u0, int u1)
{
    __shared__ __align__(16) unsigned short As[64 * 128];
    const int g = blockIdx.x >> 1, r = blockIdx.x & 1;
    if (r == 1) {                               // ---- GEMM role ----
        int u = u0 + g;
        if (u < u1)
            gemm_unit(u, nfeats, dst_feats, WT, b_ns, f_ni, h_src, f_nj, As,
                      Ns, Nd, nBlkNf, nBlkDj);
        return;
    }
    // ---- histogram role ----
    int i = g * 256 + threadIdx.x;
    if (i < E) rank[i] = atomicAdd(&cnt[dst[i]], 1);   // rank = old count
}

// -------- scat_gemm: atomic-free CSR scatter || GEMM units [u0,u1) ----------
// The ~800K random 8-B stores (the other phase floor) hide the second GEMM
// half. Runs after scan_all (needs row_ptr); its GEMM outputs are consumed
// only by fused_agg.
__global__ __launch_bounds__(256) void scat_gemm(
    const float* __restrict__ nfeats, const float* __restrict__ dst_feats,
    const unsigned short* __restrict__ WT, const float* __restrict__ b_ns,
    const int* __restrict__ src, const int* __restrict__ dst,
    const float* __restrict__ reward, const int* __restrict__ row_ptr,
    const int* __restrict__ rank, int2* __restrict__ sr_s,
    unsigned short* __restrict__ f_ni, unsigned short* __restrict__ h_src,
    unsigned short* __restrict__ f_nj,
    int Ns, int Nd, int E, int nBlkNf, int nBlkDj, int u0, int u1)
{
    __shared__ __align__(16) unsigned short As[64 * 128];
    const int g = blockIdx.x >> 1, r = blockIdx.x & 1;
    if (r == 1) {                               // ---- GEMM role ----
        int u = u0 + g;
        if (u < u1)
            gemm_unit(u, nfeats, dst_feats, WT, b_ns, f_ni, h_src, f_nj, As,
                      Ns, Nd, nBlkNf, nBlkDj);
        return;
    }
    // ---- scatter role (atomic-free) ----
    int i = g * 256 + threadIdx.x;
    if (i >= E) return;
    int d = dst[i];
    sr_s[row_ptr[d] + rank[i]] = make_int2(src[i], __float_as_int(reward[i]));
}

// ------- fused logits + softmax + aggregation: head-aligned gather ----------
// (byte-identical to the proven round-7/10/11 version: ~69us, VGPR 36,
// occ ~60%, 0 bank conflicts.)
struct G { uint2 ui; uint4 h0; uint4 h1; };
__device__ __forceinline__ G gatherE(const unsigned short* __restrict__ f_ni,
                                     const unsigned short* __restrict__ h_src,
                                     int sn, int ll, int hq) {
    G g;
    g.ui = *reinterpret_cast<const uint2*>(f_ni + (size_t)sn * HE + 4 * ll);
    const unsigned short* hp = h_src + (size_t)sn * HN + hq;
    g.h0 = *reinterpret_cast<const uint4*>(hp);
    g.h1 = *reinterpret_cast<const uint4*>(hp + 8);
    return g;
}

__global__ __launch_bounds__(256) void fused_agg(
    const unsigned short* __restrict__ f_ni, const unsigned short* __restrict__ f_nj,
    const unsigned short* __restrict__ h_src, const int2* __restrict__ sr_s,
    const int* __restrict__ row_ptr,
    const float* __restrict__ wsum, const float* __restrict__ b_e,
    const float* __restrict__ attn, float* __restrict__ out, int Nd)
{
    __shared__ float red[4][1024];
    const int wv = threadIdx.x >> 6, lane = threadIdx.x & 63;
    const int d = blockIdx.x * 4 + wv;
    if (d >= Nd) return;
    const int ll = lane & 15, sub = lane >> 4;
    const int hq = ((lane >> 2) & 3) * 64 + (lane & 3) * 16;  // head*64 + chunk*16
    const int mql = (lane >> 1) & 3;                          // write swizzle

    // wave-invariant per-lane constants
    float4 wsv = *reinterpret_cast<const float4*>(wsum + 4 * ll);
    float4 bev = *reinterpret_cast<const float4*>(b_e + 4 * ll);
    float4 atv = *reinterpret_cast<const float4*>(attn + 4 * ll);
    f32x2 ws01 = {wsv.x, wsv.y}, ws23 = {wsv.z, wsv.w};
    f32x2 at01 = {atv.x, atv.y}, at23 = {atv.z, atv.w};
    const f32x2 lk2 = {LEAKY, LEAKY};

    const int beg = row_ptr[d];
    const int end = row_ptr[d + 1];
    const int deg = end - beg;

    float den = 0.f;
    f32x2 a0 = {}, a1 = {}, a2 = {}, a3 = {}, a4 = {}, a5 = {}, a6 = {}, a7 = {};

    if (deg > 0) {
        uint2 uj = *reinterpret_cast<const uint2*>(f_nj + (size_t)d * HE + 4 * ll);
        f32x2 bb01 = bfcvt2(uj.x) + (f32x2){bev.x, bev.y};
        f32x2 bb23 = bfcvt2(uj.y) + (f32x2){bev.z, bev.w};
        const int nq = (deg + 3) >> 2;
        const int last = end - 1;

#define LDSR(q) ({ int qq_ = ((q) < nq) ? (q) : (nq - 1);                 \
                   int slot_ = beg + qq_ * 4 + sub;                       \
                   if (slot_ > last) slot_ = last;                        \
                   sr_s[slot_]; })

#define COMPUTE(sr, gg, kq) do {                                          \
    float r_ = __int_as_float((sr).y);                                    \
    f32x2 r2_ = {r_, r_};                                                 \
    f32x2 v01_ = bfcvt2((gg).ui.x) + r2_ * ws01 + bb01;                   \
    f32x2 v23_ = bfcvt2((gg).ui.y) + r2_ * ws23 + bb23;                   \
    v01_ = __builtin_elementwise_max(v01_, v01_ * lk2);                   \
    v23_ = __builtin_elementwise_max(v23_, v23_ * lk2);                   \
    f32x2 t2_ = v01_ * at01 + v23_ * at23;                                \
    float t_ = t2_.x + t2_.y;                                             \
    t_ += __shfl_xor(t_, 1);                                              \
    t_ += __shfl_xor(t_, 2);                                              \
    float ev_ = ((beg + (kq) * 4 + sub) < end) ? __expf(t_) : 0.f;        \
    den += ev_;                                                           \
    f32x2 ev2_ = {ev_, ev_};                                              \
    a0 += bfcvt2((gg).h0.x) * ev2_;                                       \
    a1 += bfcvt2((gg).h0.y) * ev2_;                                       \
    a2 += bfcvt2((gg).h0.z) * ev2_;                                       \
    a3 += bfcvt2((gg).h0.w) * ev2_;                                       \
    a4 += bfcvt2((gg).h1.x) * ev2_;                                       \
    a5 += bfcvt2((gg).h1.y) * ev2_;                                       \
    a6 += bfcvt2((gg).h1.z) * ev2_;                                       \
    a7 += bfcvt2((gg).h1.w) * ev2_;                                       \
} while (0)

        int2 sr0 = LDSR(0), sr1 = LDSR(1);
        G gA = gatherE(f_ni, h_src, sr0.x, ll, hq);
        for (int k = 0; k < nq; ++k) {
            int2 sr2 = LDSR(k + 2);
            G gB = gatherE(f_ni, h_src, sr1.x, ll, hq);
            COMPUTE(sr0, gA, k);
            sr0 = sr1; sr1 = sr2; gA = gB;
        }
#undef COMPUTE
#undef LDSR
    }

    // ---- epilogue: per-head den (lane's own head), swizzled LDS reduce ----
    den += __shfl_xor(den, 16);
    den += __shfl_xor(den, 32);           // lane now has ITS head's total
    float sc = (den > 0.f) ? 0.25f / den : 0.f;
    float* wr = &red[wv][lane * 16];
    float4 s0 = {a0.x * sc, a0.y * sc, a1.x * sc, a1.y * sc};
    float4 s1 = {a2.x * sc, a2.y * sc, a3.x * sc, a3.y * sc};
    float4 s2 = {a4.x * sc, a4.y * sc, a5.x * sc, a5.y * sc};
    float4 s3 = {a6.x * sc, a6.y * sc, a7.x * sc, a7.y * sc};
    *reinterpret_cast<float4*>(wr + ((0 ^ mql) << 2)) = s0;
    *reinterpret_cast<float4*>(wr + ((1 ^ mql) << 2)) = s1;
    *reinterpret_cast<float4*>(wr + ((2 ^ mql) << 2)) = s2;
    *reinterpret_cast<float4*>(wr + ((3 ^ mql) << 2)) = s3;
    asm volatile("s_waitcnt lgkmcnt(0)" ::: "memory");
    float ssum = 0.f;
    const int e = lane & 15, c45 = lane >> 4;
#pragma unroll
    for (int s = 0; s < 4; ++s)
#pragma unroll
        for (int h = 0; h < 4; ++h) {
            int L = s * 16 + h * 4 + c45;          // writer lane
            int m2 = (L >> 1) & 3;                 // its swizzle
            int fi = L * 16 + (((e >> 2) ^ m2) << 2) + (e & 3);
            ssum += red[wv][fi];
        }
    out[(size_t)d * OUT_NODE + lane] = fmaxf(ssum, 0.f);
}

static inline char* align256(char* p) {
    return (char*)(((uintptr_t)p + 255) & ~(uintptr_t)255);
}

extern "C" void kernel_launch(void* const* d_in, const int* in_sizes, int n_in,
                              void* d_out, int out_size, void* d_ws, size_t ws_size,
                              hipStream_t stream) {
    const float* nfeats    = (const float*)d_in[0];
    const float* dst_feats = (const float*)d_in[1];
    const float* reward    = (const float*)d_in[2];
    const int*   src       = (const int*)d_in[3];
    const int*   dst       = (const int*)d_in[4];
    const float* W_ns      = (const float*)d_in[5];
    const float* b_ns      = (const float*)d_in[6];
    const float* W_ni      = (const float*)d_in[7];
    const float* W_nj      = (const float*)d_in[8];
    const float* W_fij     = (const float*)d_in[9];
    const float* attn      = (const float*)d_in[10];
    const float* b_e       = (const float*)d_in[11];
    float* out = (float*)d_out;

    const int Ns = in_sizes[0] / IN_NODE;
    const int Nd = in_sizes[1] / IN_NODE;
    const int E  = in_sizes[2];

    char* ws = (char*)d_ws;
    unsigned short* f_ni  = (unsigned short*)ws; ws = align256(ws + (size_t)Ns * HE * 2);
    unsigned short* f_nj  = (unsigned short*)ws; ws = align256(ws + (size_t)Nd * HE * 2);
    unsigned short* h_src = (unsigned short*)ws; ws = align256(ws + (size_t)Ns * HN * 2);
    unsigned short* WT    = (unsigned short*)ws; ws = align256(ws + 49152 * 2);
    float* wsum    = (float*)ws; ws = align256(ws + HE * 4);
    int*   cnt     = (int*)ws;   // cnt + flags zeroed by one memset
    int*   flags   = cnt + Nd;   ws = align256(ws + (size_t)(Nd + 64) * 4);
    int*   row_ptr = (int*)ws;   ws = align256(ws + (size_t)(Nd + 1) * 4);
    int*   partials= (int*)ws;   ws = align256(ws + 256 * 4);
    int2*  sr_s    = (int2*)ws;  ws = align256(ws + (size_t)E * 8);
    int*   rank    = (int*)ws;   ws = align256(ws + (size_t)E * 4);

    hipMemsetAsync(cnt, 0, (size_t)(Nd + 64) * 4, stream);

    prep_w<<<13, 256, 0, stream>>>(W_fij, W_ni, W_ns, W_nj, wsum, WT);

    int nBlkNf = (Ns + 63) / 64;
    int nBlkDj = (Nd + 63) / 64;
    int nU  = 2 * nBlkNf + nBlkDj;         // total gemm units
    int nUA = (nU + 1) / 2;                // half-A (with hist), half-B (with scatter)
    int nE256 = (E + 255) / 256;           // edge blocks (hist / scatter)

    int g1 = (nE256 > nUA) ? nE256 : nUA;
    hist_gemm<<<g1 * 2, 256, 0, stream>>>(
        nfeats, dst_feats, WT, b_ns, dst, cnt, rank,
        f_ni, h_src, f_nj, Ns, Nd, E, nBlkNf, nBlkDj, 0, nUA);

    int nb = (Nd + 1023) / 1024;
    scan_all<<<nb, 256, 0, stream>>>(cnt, row_ptr, partials, flags, Nd, E, nb);

    int nUB = nU - nUA;
    int g3 = (nE256 > nUB) ? nE256 : nUB;
    scat_gemm<<<g3 * 2, 256, 0, stream>>>(
        nfeats, dst_feats, WT, b_ns, src, dst, reward, row_ptr, rank, sr_s,
        f_ni, h_src, f_nj, Ns, Nd, E, nBlkNf, nBlkDj, nUA, nU);

    fused_agg<<<(Nd + 3) / 4, 256, 0, stream>>>(
        f_ni, f_nj, h_src, sr_s, row_ptr, wsum, b_e, attn, out, Nd);
}

// Round 14
// 252.476 us; speedup vs baseline: 1.0281x; 1.0024x over previous
//
#include <hip/hip_runtime.h>

#define IN_NODE 128
#define OUT_NODE 64
#define NHEAD 4
#define HN 256                 // NHEAD * OUT_NODE
#define HE 64                  // NHEAD * OUT_EDGE
#define LEAKY 0.01f

typedef __attribute__((ext_vector_type(8))) short bf16x8;
typedef __attribute__((ext_vector_type(4))) float f32x4;
typedef __attribute__((ext_vector_type(2))) float f32x2;

__device__ __forceinline__ float bf2f(unsigned short u) {
    union { unsigned u; float f; } v; v.u = ((unsigned)u) << 16; return v.f;
}
__device__ __forceinline__ unsigned short f2bf(float x) {
    union { float f; unsigned u; } v; v.f = x;
    unsigned r = v.u + 0x7FFF + ((v.u >> 16) & 1);   // RNE
    return (unsigned short)(r >> 16);
}
__device__ __forceinline__ bf16x8 cvt8(float4 a, float4 b) {
    bf16x8 r;
    r[0] = (short)f2bf(a.x); r[1] = (short)f2bf(a.y);
    r[2] = (short)f2bf(a.z); r[3] = (short)f2bf(a.w);
    r[4] = (short)f2bf(b.x); r[5] = (short)f2bf(b.y);
    r[6] = (short)f2bf(b.z); r[7] = (short)f2bf(b.w);
    return r;
}
// one dword holding 2 bf16 -> 2 f32 (lo = element 2k, hi = element 2k+1)
__device__ __forceinline__ f32x2 bfcvt2(unsigned d) {
    union { unsigned u; float f; } lo, hi;
    lo.u = d << 16; hi.u = d & 0xFFFF0000u;
    f32x2 r; r.x = lo.f; r.y = hi.f; return r;
}

// ------ prep_z: wsum (block 0) + W -> fragment bf16 WB (1..12)
//        + zero cnt/flags (blocks 13..) -- replaces the hipMemsetAsync node.
__global__ void prep_z(const float* __restrict__ W_fij,
                       const float* __restrict__ W_ni,
                       const float* __restrict__ W_ns,
                       const float* __restrict__ W_nj,
                       float* __restrict__ wsum, unsigned short* __restrict__ WT,
                       int* __restrict__ cnt, int nZero) {
    int b = blockIdx.x;
    if (b == 0) {
        int k = threadIdx.x;
        if (k < 64) {
            float s = 0.f;
#pragma unroll
            for (int c = 0; c < 16; ++c) s += W_fij[c * 64 + k];
            wsum[k] = s;
        }
        return;
    }
    if (b <= 12) {
        int base = (b - 1) * 4096 + threadIdx.x;
#pragma unroll
        for (int i = 0; i < 16; ++i) {
            int idx = base + i * 256;
            int g   = idx >> 11;          // group (24)
            int rem = idx & 2047;
            int c   = rem >> 9;           // K-chunk (4)
            int l   = (rem >> 3) & 63;    // lane
            int j   = rem & 7;            // element within fragment
            int nl  = l & 15;
            int k   = c * 32 + (l >> 4) * 8 + j;
            unsigned short v;
            if (g < 4)       v = f2bf(W_ni[k * 64  + g * 16 + nl]);
            else if (g < 20) v = f2bf(W_ns[k * 256 + (g - 4) * 16 + nl]);
            else             v = f2bf(W_nj[k * 64  + (g - 20) * 16 + nl]);
            WT[idx] = v;
        }
        return;
    }
    // zero role: 1024 ints per block (guarded)
    int base = (b - 13) * 1024 + threadIdx.x * 4;
#pragma unroll
    for (int j = 0; j < 4; ++j)
        if (base + j < nZero) cnt[base + j] = 0;
}

// ---- GEMM tile: 64 rows of A x (NG*16) output cols, A staged in LDS once ---
template<int NG, int G0>
__device__ __forceinline__ void gemm_tile(
    const float* __restrict__ A, int rowBase, int M,
    const unsigned short* __restrict__ WB, const float* __restrict__ b_ns,
    unsigned short* __restrict__ f_ni, unsigned short* __restrict__ h_src,
    unsigned short* __restrict__ f_nj, unsigned short* As)
{
    const int t = threadIdx.x;
    const float4* A4 = reinterpret_cast<const float4*>(A);
#pragma unroll
    for (int j = 0; j < 4; ++j) {
        int gi = j * 256 + t;            // granule index (8 floats)
        int r  = gi >> 4;                // tile row (0..63)
        int gr = rowBase + r; if (gr >= M) gr = M - 1;   // clamp, stores guarded
        int fi = (gi & 15) * 2;          // float4 index within row
        float4 a0 = A4[(size_t)gr * 32 + fi];
        float4 a1 = A4[(size_t)gr * 32 + fi + 1];
        int byteoff = (gi * 16) ^ ((r & 7) << 4);
        *reinterpret_cast<bf16x8*>(reinterpret_cast<char*>(As) + byteoff) = cvt8(a0, a1);
    }
    __syncthreads();

    const int lane = t & 63, w = t >> 6;
    const int rw = rowBase + w * 16;
    if (rw >= M) return;                 // tail wave, nothing to compute
    const int m = lane & 15, q = lane >> 4;
    const int tr = w * 16 + m;

    f32x4 acc[NG] = {};
    const char* Asb = reinterpret_cast<const char*>(As);
#pragma unroll
    for (int c = 0; c < 4; ++c) {
        int gi  = tr * 16 + c * 4 + q;
        int off = (gi * 16) ^ ((tr & 7) << 4);
        bf16x8 af = *reinterpret_cast<const bf16x8*>(Asb + off);
#pragma unroll
        for (int g = 0; g < NG; ++g) {
            bf16x8 bf = *reinterpret_cast<const bf16x8*>(
                WB + (size_t)(((G0 + g) * 4 + c) * 64 + lane) * 8);
            acc[g] = __builtin_amdgcn_mfma_f32_16x16x32_bf16(af, bf, acc[g], 0, 0, 0);
        }
    }

#pragma unroll
    for (int g = 0; g < NG; ++g) {
        const int ga = G0 + g;
        unsigned short* C; int N, colBase; const float* bias = nullptr;
        if (ga < 4)       { C = f_ni;  N = 64;  colBase = ga * 16; }
        else if (ga < 20) { C = h_src; N = 256; colBase = (ga - 4) * 16; bias = b_ns; }
        else              { C = f_nj;  N = 64;  colBase = (ga - 20) * 16; }
        int col = colBase + m;
        float bv = bias ? bias[col] : 0.f;
#pragma unroll
        for (int rr = 0; rr < 4; ++rr) {
            int orow = rw + q * 4 + rr;
            if (orow < M) C[(size_t)orow * N + col] = f2bf(acc[g][rr] + bv);
        }
    }
}

// GEMM unit decode shared by the mixed kernels: unit u in [0, 2*nBlkNf+nBlkDj)
__device__ __forceinline__ void gemm_unit(
    int u, const float* __restrict__ nfeats, const float* __restrict__ dst_feats,
    const unsigned short* __restrict__ WT, const float* __restrict__ b_ns,
    unsigned short* __restrict__ f_ni, unsigned short* __restrict__ h_src,
    unsigned short* __restrict__ f_nj, unsigned short* As,
    int Ns, int Nd, int nBlkNf, int nBlkDj)
{
    if (u < 2 * nBlkNf) {
        int tile = u >> 1;
        if ((u & 1) == 0)
            gemm_tile<10, 0>(nfeats, tile * 64, Ns, WT, b_ns, f_ni, h_src, f_nj, As);
        else
            gemm_tile<10, 10>(nfeats, tile * 64, Ns, WT, b_ns, f_ni, h_src, f_nj, As);
    } else if (u < 2 * nBlkNf + nBlkDj) {
        gemm_tile<4, 20>(dst_feats, (u - 2 * nBlkNf) * 64, Nd, WT, b_ns, f_ni, h_src, f_nj, As);
    }
}

// -------- hist_gemm: degree histogram (rank capture) || GEMM units [u0,u1) --
__global__ __launch_bounds__(256) void hist_gemm(
    const float* __restrict__ nfeats, const float* __restrict__ dst_feats,
    const unsigned short* __restrict__ WT, const float* __restrict__ b_ns,
    const int* __restrict__ dst,
    int* __restrict__ cnt, int* __restrict__ rank,
    unsigned short* __restrict__ f_ni, unsigned short* __restrict__ h_src,
    unsigned short* __restrict__ f_nj,
    int Ns, int Nd, int E, int nBlkNf, int nBlkDj, int u0, int u1)
{
    __shared__ __align__(16) unsigned short As[64 * 128];
    const int g = blockIdx.x >> 1, r = blockIdx.x & 1;
    if (r == 1) {                               // ---- GEMM role ----
        int u = u0 + g;
        if (u < u1)
            gemm_unit(u, nfeats, dst_feats, WT, b_ns, f_ni, h_src, f_nj, As,
                      Ns, Nd, nBlkNf, nBlkDj);
        return;
    }
    // ---- histogram role ----
    int i = g * 256 + threadIdx.x;
    if (i < E) rank[i] = atomicAdd(&cnt[dst[i]], 1);   // rank = old count
}

// -------- scan_gemm: exclusive scan of cnt -> row_ptr || GEMM units [u0,u1) -
// Scan role blocks (g < nb) run the proven scan_all protocol; all blocks of
// this dispatch are co-resident (grid << capacity) so the acquire/release
// spin across scan blocks is safe. GEMM role hides the scan's ~10us.
__global__ __launch_bounds__(256) void scan_gemm(
    const int* __restrict__ cnt, int* __restrict__ row_ptr,
    int* __restrict__ partials, int* __restrict__ flags,
    int n, int E, int nb,
    const float* __restrict__ nfeats, const float* __restrict__ dst_feats,
    const unsigned short* __restrict__ WT, const float* __restrict__ b_ns,
    unsigned short* __restrict__ f_ni, unsigned short* __restrict__ h_src,
    unsigned short* __restrict__ f_nj,
    int Ns, int Nd, int nBlkNf, int nBlkDj, int u0, int u1)
{
    __shared__ __align__(16) unsigned short As[64 * 128];
    __shared__ int sums[256];
    __shared__ int s_base;
    const int g = blockIdx.x >> 1, r = blockIdx.x & 1;
    if (r == 1) {                               // ---- GEMM role ----
        int u = u0 + g;
        if (u < u1)
            gemm_unit(u, nfeats, dst_feats, WT, b_ns, f_ni, h_src, f_nj, As,
                      Ns, Nd, nBlkNf, nBlkDj);
        return;
    }
    // ---- scan role (proven scan_all body, b := g) ----
    const int b = g;
    if (b >= nb) return;
    int tid = threadIdx.x;
    int base = b * 1024;
    int v[4]; int tsum = 0;
#pragma unroll
    for (int j = 0; j < 4; ++j) {
        int idx = base + tid * 4 + j;
        v[j] = (idx < n) ? cnt[idx] : 0;
        tsum += v[j];
    }
    sums[tid] = tsum;
    __syncthreads();
    for (int off = 1; off < 256; off <<= 1) {
        int x = (tid >= off) ? sums[tid - off] : 0;
        __syncthreads();
        sums[tid] += x;
        __syncthreads();
    }
    if (tid == 255) {
        __hip_atomic_store(&partials[b], sums[255], __ATOMIC_RELAXED, __HIP_MEMORY_SCOPE_AGENT);
        __hip_atomic_store(&flags[b], 1, __ATOMIC_RELEASE, __HIP_MEMORY_SCOPE_AGENT);
    }
    if (tid < 64) {
        int val = 0;
        if (tid < nb) {
            while (__hip_atomic_load(&flags[tid], __ATOMIC_ACQUIRE, __HIP_MEMORY_SCOPE_AGENT) == 0) {
                __builtin_amdgcn_s_sleep(1);
            }
            val = __hip_atomic_load(&partials[tid], __ATOMIC_RELAXED, __HIP_MEMORY_SCOPE_AGENT);
        }
#pragma unroll
        for (int o = 1; o < 64; o <<= 1) {
            int x = __shfl_up(val, o);
            if (tid >= o) val += x;
        }
        int off = (b > 0) ? __shfl(val, b - 1) : 0;
        if (tid == 0) s_base = off;
    }
    __syncthreads();
    int run = s_base + sums[tid] - tsum;   // global exclusive prefix
#pragma unroll
    for (int j = 0; j < 4; ++j) {
        int idx = base + tid * 4 + j;
        if (idx < n) row_ptr[idx] = run;
        run += v[j];
    }
    if (b == nb - 1 && tid == 0) row_ptr[n] = E;
}

// -------- scat_gemm: atomic-free CSR scatter || GEMM units [u0,u1) ----------
__global__ __launch_bounds__(256) void scat_gemm(
    const float* __restrict__ nfeats, const float* __restrict__ dst_feats,
    const unsigned short* __restrict__ WT, const float* __restrict__ b_ns,
    const int* __restrict__ src, const int* __restrict__ dst,
    const float* __restrict__ reward, const int* __restrict__ row_ptr,
    const int* __restrict__ rank, int2* __restrict__ sr_s,
    unsigned short* __restrict__ f_ni, unsigned short* __restrict__ h_src,
    unsigned short* __restrict__ f_nj,
    int Ns, int Nd, int E, int nBlkNf, int nBlkDj, int u0, int u1)
{
    __shared__ __align__(16) unsigned short As[64 * 128];
    const int g = blockIdx.x >> 1, r = blockIdx.x & 1;
    if (r == 1) {                               // ---- GEMM role ----
        int u = u0 + g;
        if (u < u1)
            gemm_unit(u, nfeats, dst_feats, WT, b_ns, f_ni, h_src, f_nj, As,
                      Ns, Nd, nBlkNf, nBlkDj);
        return;
    }
    // ---- scatter role (atomic-free) ----
    int i = g * 256 + threadIdx.x;
    if (i >= E) return;
    int d = dst[i];
    sr_s[row_ptr[d] + rank[i]] = make_int2(src[i], __float_as_int(reward[i]));
}

// ------- fused logits + softmax + aggregation: head-aligned gather ----------
// (byte-identical to the proven round-7..12 version: ~69us, VGPR 36,
// occ ~60%, 0 bank conflicts.)
struct G { uint2 ui; uint4 h0; uint4 h1; };
__device__ __forceinline__ G gatherE(const unsigned short* __restrict__ f_ni,
                                     const unsigned short* __restrict__ h_src,
                                     int sn, int ll, int hq) {
    G g;
    g.ui = *reinterpret_cast<const uint2*>(f_ni + (size_t)sn * HE + 4 * ll);
    const unsigned short* hp = h_src + (size_t)sn * HN + hq;
    g.h0 = *reinterpret_cast<const uint4*>(hp);
    g.h1 = *reinterpret_cast<const uint4*>(hp + 8);
    return g;
}

__global__ __launch_bounds__(256) void fused_agg(
    const unsigned short* __restrict__ f_ni, const unsigned short* __restrict__ f_nj,
    const unsigned short* __restrict__ h_src, const int2* __restrict__ sr_s,
    const int* __restrict__ row_ptr,
    const float* __restrict__ wsum, const float* __restrict__ b_e,
    const float* __restrict__ attn, float* __restrict__ out, int Nd)
{
    __shared__ float red[4][1024];
    const int wv = threadIdx.x >> 6, lane = threadIdx.x & 63;
    const int d = blockIdx.x * 4 + wv;
    if (d >= Nd) return;
    const int ll = lane & 15, sub = lane >> 4;
    const int hq = ((lane >> 2) & 3) * 64 + (lane & 3) * 16;  // head*64 + chunk*16
    const int mql = (lane >> 1) & 3;                          // write swizzle

    // wave-invariant per-lane constants
    float4 wsv = *reinterpret_cast<const float4*>(wsum + 4 * ll);
    float4 bev = *reinterpret_cast<const float4*>(b_e + 4 * ll);
    float4 atv = *reinterpret_cast<const float4*>(attn + 4 * ll);
    f32x2 ws01 = {wsv.x, wsv.y}, ws23 = {wsv.z, wsv.w};
    f32x2 at01 = {atv.x, atv.y}, at23 = {atv.z, atv.w};
    const f32x2 lk2 = {LEAKY, LEAKY};

    const int beg = row_ptr[d];
    const int end = row_ptr[d + 1];
    const int deg = end - beg;

    float den = 0.f;
    f32x2 a0 = {}, a1 = {}, a2 = {}, a3 = {}, a4 = {}, a5 = {}, a6 = {}, a7 = {};

    if (deg > 0) {
        uint2 uj = *reinterpret_cast<const uint2*>(f_nj + (size_t)d * HE + 4 * ll);
        f32x2 bb01 = bfcvt2(uj.x) + (f32x2){bev.x, bev.y};
        f32x2 bb23 = bfcvt2(uj.y) + (f32x2){bev.z, bev.w};
        const int nq = (deg + 3) >> 2;
        const int last = end - 1;

#define LDSR(q) ({ int qq_ = ((q) < nq) ? (q) : (nq - 1);                 \
                   int slot_ = beg + qq_ * 4 + sub;                       \
                   if (slot_ > last) slot_ = last;                        \
                   sr_s[slot_]; })

#define COMPUTE(sr, gg, kq) do {                                          \
    float r_ = __int_as_float((sr).y);                                    \
    f32x2 r2_ = {r_, r_};                                                 \
    f32x2 v01_ = bfcvt2((gg).ui.x) + r2_ * ws01 + bb01;                   \
    f32x2 v23_ = bfcvt2((gg).ui.y) + r2_ * ws23 + bb23;                   \
    v01_ = __builtin_elementwise_max(v01_, v01_ * lk2);                   \
    v23_ = __builtin_elementwise_max(v23_, v23_ * lk2);                   \
    f32x2 t2_ = v01_ * at01 + v23_ * at23;                                \
    float t_ = t2_.x + t2_.y;                                             \
    t_ += __shfl_xor(t_, 1);                                              \
    t_ += __shfl_xor(t_, 2);                                              \
    float ev_ = ((beg + (kq) * 4 + sub) < end) ? __expf(t_) : 0.f;        \
    den += ev_;                                                           \
    f32x2 ev2_ = {ev_, ev_};                                              \
    a0 += bfcvt2((gg).h0.x) * ev2_;                                       \
    a1 += bfcvt2((gg).h0.y) * ev2_;                                       \
    a2 += bfcvt2((gg).h0.z) * ev2_;                                       \
    a3 += bfcvt2((gg).h0.w) * ev2_;                                       \
    a4 += bfcvt2((gg).h1.x) * ev2_;                                       \
    a5 += bfcvt2((gg).h1.y) * ev2_;                                       \
    a6 += bfcvt2((gg).h1.z) * ev2_;                                       \
    a7 += bfcvt2((gg).h1.w) * ev2_;                                       \
} while (0)

        int2 sr0 = LDSR(0), sr1 = LDSR(1);
        G gA = gatherE(f_ni, h_src, sr0.x, ll, hq);
        for (int k = 0; k < nq; ++k) {
            int2 sr2 = LDSR(k + 2);
            G gB = gatherE(f_ni, h_src, sr1.x, ll, hq);
            COMPUTE(sr0, gA, k);
            sr0 = sr1; sr1 = sr2; gA = gB;
        }
#undef COMPUTE
#undef LDSR
    }

    // ---- epilogue: per-head den (lane's own head), swizzled LDS reduce ----
    den += __shfl_xor(den, 16);
    den += __shfl_xor(den, 32);           // lane now has ITS head's total
    float sc = (den > 0.f) ? 0.25f / den : 0.f;
    float* wr = &red[wv][lane * 16];
    float4 s0 = {a0.x * sc, a0.y * sc, a1.x * sc, a1.y * sc};
    float4 s1 = {a2.x * sc, a2.y * sc, a3.x * sc, a3.y * sc};
    float4 s2 = {a4.x * sc, a4.y * sc, a5.x * sc, a5.y * sc};
    float4 s3 = {a6.x * sc, a6.y * sc, a7.x * sc, a7.y * sc};
    *reinterpret_cast<float4*>(wr + ((0 ^ mql) << 2)) = s0;
    *reinterpret_cast<float4*>(wr + ((1 ^ mql) << 2)) = s1;
    *reinterpret_cast<float4*>(wr + ((2 ^ mql) << 2)) = s2;
    *reinterpret_cast<float4*>(wr + ((3 ^ mql) << 2)) = s3;
    asm volatile("s_waitcnt lgkmcnt(0)" ::: "memory");
    float ssum = 0.f;
    const int e = lane & 15, c45 = lane >> 4;
#pragma unroll
    for (int s = 0; s < 4; ++s)
#pragma unroll
        for (int h = 0; h < 4; ++h) {
            int L = s * 16 + h * 4 + c45;          // writer lane
            int m2 = (L >> 1) & 3;                 // its swizzle
            int fi = L * 16 + (((e >> 2) ^ m2) << 2) + (e & 3);
            ssum += red[wv][fi];
        }
    out[(size_t)d * OUT_NODE + lane] = fmaxf(ssum, 0.f);
}

static inline char* align256(char* p) {
    return (char*)(((uintptr_t)p + 255) & ~(uintptr_t)255);
}

extern "C" void kernel_launch(void* const* d_in, const int* in_sizes, int n_in,
                              void* d_out, int out_size, void* d_ws, size_t ws_size,
                              hipStream_t stream) {
    const float* nfeats    = (const float*)d_in[0];
    const float* dst_feats = (const float*)d_in[1];
    const float* reward    = (const float*)d_in[2];
    const int*   src       = (const int*)d_in[3];
    const int*   dst       = (const int*)d_in[4];
    const float* W_ns      = (const float*)d_in[5];
    const float* b_ns      = (const float*)d_in[6];
    const float* W_ni      = (const float*)d_in[7];
    const float* W_nj      = (const float*)d_in[8];
    const float* W_fij     = (const float*)d_in[9];
    const float* attn      = (const float*)d_in[10];
    const float* b_e       = (const float*)d_in[11];
    float* out = (float*)d_out;

    const int Ns = in_sizes[0] / IN_NODE;
    const int Nd = in_sizes[1] / IN_NODE;
    const int E  = in_sizes[2];

    char* ws = (char*)d_ws;
    unsigned short* f_ni  = (unsigned short*)ws; ws = align256(ws + (size_t)Ns * HE * 2);
    unsigned short* f_nj  = (unsigned short*)ws; ws = align256(ws + (size_t)Nd * HE * 2);
    unsigned short* h_src = (unsigned short*)ws; ws = align256(ws + (size_t)Ns * HN * 2);
    unsigned short* WT    = (unsigned short*)ws; ws = align256(ws + 49152 * 2);
    float* wsum    = (float*)ws; ws = align256(ws + HE * 4);
    int*   cnt     = (int*)ws;   // cnt + flags zeroed by prep_z
    int*   flags   = cnt + Nd;   ws = align256(ws + (size_t)(Nd + 64) * 4);
    int*   row_ptr = (int*)ws;   ws = align256(ws + (size_t)(Nd + 1) * 4);
    int*   partials= (int*)ws;   ws = align256(ws + 256 * 4);
    int2*  sr_s    = (int2*)ws;  ws = align256(ws + (size_t)E * 8);
    int*   rank    = (int*)ws;   ws = align256(ws + (size_t)E * 4);

    const int nZero = Nd + 64;
    int nZblk = (nZero + 1023) / 1024;
    prep_z<<<13 + nZblk, 256, 0, stream>>>(
        W_fij, W_ni, W_ns, W_nj, wsum, WT, cnt, nZero);

    int nBlkNf = (Ns + 63) / 64;
    int nBlkDj = (Nd + 63) / 64;
    int nU  = 2 * nBlkNf + nBlkDj;         // total gemm units
    int uA  = (int)((long long)nU * 46 / 100);   // with hist
    int uS  = (int)((long long)nU * 8 / 100);    // with scan
    int nE256 = (E + 255) / 256;           // edge blocks (hist / scatter)
    int nb = (Nd + 1023) / 1024;           // scan blocks

    int g1 = (nE256 > uA) ? nE256 : uA;
    hist_gemm<<<g1 * 2, 256, 0, stream>>>(
        nfeats, dst_feats, WT, b_ns, dst, cnt, rank,
        f_ni, h_src, f_nj, Ns, Nd, E, nBlkNf, nBlkDj, 0, uA);

    int g2 = (nb > uS) ? nb : uS;
    scan_gemm<<<g2 * 2, 256, 0, stream>>>(
        cnt, row_ptr, partials, flags, Nd, E, nb,
        nfeats, dst_feats, WT, b_ns, f_ni, h_src, f_nj,
        Ns, Nd, nBlkNf, nBlkDj, uA, uA + uS);

    int uB0 = uA + uS, nUB = nU - uB0;
    int g3 = (nE256 > nUB) ? nE256 : nUB;
    scat_gemm<<<g3 * 2, 256, 0, stream>>>(
        nfeats, dst_feats, WT, b_ns, src, dst, reward, row_ptr, rank, sr_s,
        f_ni, h_src, f_nj, Ns, Nd, E, nBlkNf, nBlkDj, uB0, nU);

    fused_agg<<<(Nd + 3) / 4, 256, 0, stream>>>(
        f_ni, f_nj, h_src, sr_s, row_ptr, wsum, b_e, attn, out, Nd);
}